// Round 7
// baseline (8874.832 us; speedup 1.0000x reference)
//
#include <hip/hip_runtime.h>
#include <hip/hip_bf16.h>

typedef unsigned short u16;
typedef unsigned int u32;

#define NB 2
#define NN 384
#define ND 128
#define NE 64
#define NHD 8
#define NHID 256
#define EH1 384
#define EH2 128
#define LN_EPS 1e-5f
#define ATT_SCALE 0.17677669529663687f  // 1/sqrt(NODE_HIDDEN//HEADS)=1/sqrt(32)

#define XOUT_ELEMS (NB * NN * ND)                 // 98304
#define ADJ_ELEMS ((size_t)NB * NN * NN * NE)     // 18874368
#define OUT_ELEMS (XOUT_ELEMS + ADJ_ELEMS)        // 18972672 f32 elements
// f32 scratch carved from the TAIL of the adj-output region (dead until
// k_edge1 writes it, by which time scratch is fully consumed).
#define SCRATCH_F32 (4 * XOUT_ELEMS)              // nq,nk,nv,att

__device__ __forceinline__ float bflo(u32 u) {
  return __builtin_bit_cast(float, u << 16);
}
__device__ __forceinline__ float bfhi(u32 u) {
  return __builtin_bit_cast(float, u & 0xffff0000u);
}
__device__ __forceinline__ u16 bfr(float f) {
  return __builtin_bit_cast(u16, __float2bfloat16(f));
}
__device__ __forceinline__ u32 packbf(float a, float b) {
  return (u32)bfr(a) | ((u32)bfr(b) << 16);
}
__device__ __forceinline__ float wsum64(float v) {
#pragma unroll
  for (int o = 32; o > 0; o >>= 1) v += __shfl_xor(v, o, 64);
  return v;
}

// ---------------- K1: nq/nk/nv = x @ w{q,k,v}.T (f32, plain) ----------------
__global__ void k_node_qkv(const float* __restrict__ x,
                           const float* __restrict__ wq,
                           const float* __restrict__ wk,
                           const float* __restrict__ wv,
                           float* __restrict__ nq, float* __restrict__ nk,
                           float* __restrict__ nv) {
  int row = blockIdx.x;  // b*N+i
  int t = threadIdx.x;   // 128
  __shared__ float xs[ND];
  xs[t] = x[row * ND + t];
  __syncthreads();
  float aq = 0.f, ak = 0.f, av = 0.f;
  for (int k = 0; k < ND; ++k) {
    float xv = xs[k];
    aq += xv * wq[t * ND + k];
    ak += xv * wk[t * ND + k];
    av += xv * wv[t * ND + k];
  }
  nq[row * ND + t] = aq;
  nk[row * ND + t] = ak;
  nv[row * ND + t] = av;
}

// ---------------- K2: attention, braindead-obvious version ----------------
struct AttnS {
  u16 wq_t[NE][ND];  // [k][c] = bf16(weq[c][k])
  u16 wk_t[NE][ND];
  u16 wv_t[NE][ND];
  float sc[NHD][NN];
};

__global__ void k_attn(const float* __restrict__ adj,
                       const float* __restrict__ weq,
                       const float* __restrict__ wek,
                       const float* __restrict__ wev,
                       const float* __restrict__ nq,
                       const float* __restrict__ nk,
                       const float* __restrict__ nv,
                       float* __restrict__ att) {
  __shared__ AttnS s;
  int bi = blockIdx.x;
  int b = bi / NN;
  int t = threadIdx.x;  // 384

  for (int e = t; e < ND * NE; e += 384) {
    int c = e >> 6, k = e & 63;
    s.wq_t[k][c] = bfr(weq[e]);
    s.wk_t[k][c] = bfr(wek[e]);
    s.wv_t[k][c] = bfr(wev[e]);
  }
  __syncthreads();

  // pass 1: scores. thread t = key index j.
  {
    int j = t;
    const float* arow = adj + ((size_t)bi * NN + j) * NE;
    for (int h = 0; h < NHD; ++h) {
      float sacc = 0.f;
      for (int dd = 0; dd < 16; dd += 2) {
        int c = h * 16 + dd;
        float q0 = nq[bi * ND + c], q1 = nq[bi * ND + c + 1];
        float k0 = nk[(b * NN + j) * ND + c], k1 = nk[(b * NN + j) * ND + c + 1];
        for (int k = 0; k < NE; ++k) {
          float a = arow[k];
          u32 wq2 = *(const u32*)&s.wq_t[k][c];
          u32 wk2 = *(const u32*)&s.wk_t[k][c];
          q0 += a * bflo(wq2); q1 += a * bfhi(wq2);
          k0 += a * bflo(wk2); k1 += a * bfhi(wk2);
        }
        sacc += q0 * k0 + q1 * k1;
      }
      s.sc[h][j] = sacc * ATT_SCALE;
    }
  }
  __syncthreads();

  // softmax over j, fully serial per head (threads 0..7)
  if (t < NHD) {
    int h = t;
    float m = -1e30f;
    for (int j = 0; j < NN; ++j) m = fmaxf(m, s.sc[h][j]);
    float sum = 0.f;
    for (int j = 0; j < NN; ++j) {
      float e = __expf(s.sc[h][j] - m);
      s.sc[h][j] = e;
      sum += e;
    }
    float r = 1.f / sum;
    for (int j = 0; j < NN; ++j) s.sc[h][j] *= r;
  }
  __syncthreads();

  // pass 2: PV. threads 0..63 handle channels 2t, 2t+1.
  if (t < NE) {
    int c0 = 2 * t;
    int h = t >> 3;  // = c0/16
    float o0 = 0.f, o1 = 0.f;
    for (int j = 0; j < NN; ++j) {
      float p = s.sc[h][j];
      const float* arow = adj + ((size_t)bi * NN + j) * NE;
      float v0 = nv[(b * NN + j) * ND + c0];
      float v1 = nv[(b * NN + j) * ND + c0 + 1];
      for (int k = 0; k < NE; ++k) {
        float a = arow[k];
        u32 wv2 = *(const u32*)&s.wv_t[k][c0];
        v0 += a * bflo(wv2);
        v1 += a * bfhi(wv2);
      }
      o0 += p * v0;
      o1 += p * v1;
    }
    // channel c -> (h=c/16, d=c%16); output position d*HEADS + h
    att[bi * ND + (c0 & 15) * NHD + h] = o0;
    att[bi * ND + ((c0 + 1) & 15) * NHD + h] = o1;
  }
}

// ---------------- K3: nfc1 + LN1 + FFN + LN2, serial LN reductions ---------
struct FfnS {
  float atts[ND];
  float tvb[ND];
  float x1[ND];
  float hb[NHID];
  float stats[2];  // mean, rstd
};

__global__ void k_node_ffn(const float* __restrict__ x,
                           const float* __restrict__ att,
                           const float* __restrict__ w1, const float* __restrict__ b1,
                           const float* __restrict__ g1, const float* __restrict__ bb1,
                           const float* __restrict__ w2, const float* __restrict__ b2,
                           const float* __restrict__ w3, const float* __restrict__ b3,
                           const float* __restrict__ g2, const float* __restrict__ bb2,
                           float* __restrict__ xout) {
  __shared__ FfnS s;
  int row = blockIdx.x;
  int tid = threadIdx.x;  // 256
  if (tid < ND) s.atts[tid] = att[row * ND + tid];
  __syncthreads();

  if (tid < ND) {
    float acc = b1[tid];
    for (int k = 0; k < ND; ++k) acc += s.atts[k] * w1[tid * ND + k];
    s.tvb[tid] = x[row * ND + tid] + acc;
  }
  __syncthreads();
  if (tid == 0) {
    float m = 0.f;
    for (int k = 0; k < ND; ++k) m += s.tvb[k];
    m *= (1.f / ND);
    float v = 0.f;
    for (int k = 0; k < ND; ++k) { float d = s.tvb[k] - m; v += d * d; }
    s.stats[0] = m;
    s.stats[1] = rsqrtf(v * (1.f / ND) + LN_EPS);
  }
  __syncthreads();
  if (tid < ND)
    s.x1[tid] = (s.tvb[tid] - s.stats[0]) * s.stats[1] * g1[tid] + bb1[tid];
  __syncthreads();

  {
    float acc = b2[tid];
    for (int k = 0; k < ND; ++k) acc += s.x1[k] * w2[tid * ND + k];
    s.hb[tid] = fmaxf(acc, 0.f);
  }
  __syncthreads();

  if (tid < ND) {
    float acc = b3[tid];
    for (int k = 0; k < NHID; ++k) acc += s.hb[k] * w3[tid * NHID + k];
    s.tvb[tid] = s.x1[tid] + acc;
  }
  __syncthreads();
  if (tid == 0) {
    float m = 0.f;
    for (int k = 0; k < ND; ++k) m += s.tvb[k];
    m *= (1.f / ND);
    float v = 0.f;
    for (int k = 0; k < ND; ++k) { float d = s.tvb[k] - m; v += d * d; }
    s.stats[0] = m;
    s.stats[1] = rsqrtf(v * (1.f / ND) + LN_EPS);
  }
  __syncthreads();
  if (tid < ND) {
    float o = (s.tvb[tid] - s.stats[0]) * s.stats[1] * g2[tid] + bb2[tid];
    xout[row * ND + tid] = o;  // FLOAT32 output
  }
}

// ---------------- K4: edge update stage 1, block per (b,i), wave per j ------
// x2 (post-LN2 node features) read from the f32 x-output region of d_out.
struct E1S {
  u32 e1p[EH1 / 2][NE];  // 48KB bf16-pair weights
  u32 e2p[NE / 2][NE];   // 8KB
  float ua[4][EH1];
  float hbf[4][NE];
  float xi[ND];
};

__global__ void k_edge1(const float* __restrict__ adj,
                        const float* __restrict__ xq,
                        const float* __restrict__ w1, const float* __restrict__ b1,
                        const float* __restrict__ w2, const float* __restrict__ b2,
                        const float* __restrict__ g, const float* __restrict__ bb,
                        float* __restrict__ adj1out) {
  __shared__ E1S s;
  int bi = blockIdx.x;
  int b = bi / NN, i = bi % NN;
  int tid = threadIdx.x;  // 256
  int w = tid >> 6, l = tid & 63;

  const float2* w1f = (const float2*)w1;
  for (int p = tid; p < NE * (EH1 / 2); p += 256) {
    int li = p / (EH1 / 2), k2 = p % (EH1 / 2);
    float2 v = w1f[p];
    s.e1p[k2][li] = packbf(v.x, v.y);
  }
  const float2* w2f = (const float2*)w2;
  for (int p = tid; p < NE * (NE / 2); p += 256) {
    int c = p / (NE / 2), l2 = p % (NE / 2);
    float2 v = w2f[p];
    s.e2p[l2][c] = packbf(v.x, v.y);
  }
  if (tid < ND) s.xi[tid] = xq[bi * ND + tid];
  __syncthreads();

  s.ua[w][256 + l] = s.xi[l];  // tgt x_i, constant per block
  s.ua[w][320 + l] = s.xi[64 + l];
  float bias1 = b1[l];
  float bias2 = b2[l];
  float gl = g[l];
  float bl = bb[l];

  for (int j = w; j < NN; j += 4) {
    float aij = adj[((size_t)bi * NN + j) * NE + l];
    s.ua[w][l] = aij;
    s.ua[w][64 + l] = adj[((size_t)(b * NN + j) * NN + i) * NE + l];
    s.ua[w][128 + l] = xq[(b * NN + j) * ND + l];  // src x_j
    s.ua[w][192 + l] = xq[(b * NN + j) * ND + 64 + l];
    float acc = bias1;
    const float2* ua2 = (const float2*)s.ua[w];
#pragma unroll 4
    for (int k2 = 0; k2 < EH1 / 2; ++k2) {
      float2 uv = ua2[k2];
      u32 wp = s.e1p[k2][l];
      acc += uv.x * bflo(wp) + uv.y * bfhi(wp);
    }
    float h = fmaxf(acc, 0.f);
    s.hbf[w][l] = h;
    float r = bias2;
    const float2* h2 = (const float2*)s.hbf[w];
#pragma unroll 4
    for (int l2 = 0; l2 < NE / 2; ++l2) {
      float2 hv = h2[l2];
      u32 wp = s.e2p[l2][l];
      r += hv.x * bflo(wp) + hv.y * bfhi(wp);
    }
    float tv = aij + r;
    float mean = wsum64(tv) * (1.f / NE);
    float dv = tv - mean;
    float var = wsum64(dv * dv) * (1.f / NE);
    float o = dv * rsqrtf(var + LN_EPS) * gl + bl;
    adj1out[((size_t)bi * NN + j) * NE + l] = o;  // FLOAT32 output
  }
}

// ---------------- K5: edge update stage 2 (in-place on d_out adj, f32) -----
struct E2S {
  u32 e3p[NE / 2][EH2];  // 16KB
  u32 e4p[EH2 / 2][NE];  // 16KB
  float tb[8][NE];
  float h2b[8][EH2];
};

__global__ void k_edge2(float* __restrict__ adjio,
                        const float* __restrict__ w3, const float* __restrict__ b3,
                        const float* __restrict__ w4, const float* __restrict__ b4,
                        const float* __restrict__ g, const float* __restrict__ bb) {
  __shared__ E2S s;
  int bi = blockIdx.x;
  int tid = threadIdx.x;  // 512
  int w = tid >> 6, l = tid & 63;

  const float2* w3f = (const float2*)w3;
  for (int p = tid; p < EH2 * (NE / 2); p += 512) {
    int uu = p / (NE / 2), k2 = p % (NE / 2);
    float2 v = w3f[p];
    s.e3p[k2][uu] = packbf(v.x, v.y);
  }
  const float2* w4f = (const float2*)w4;
  for (int p = tid; p < NE * (EH2 / 2); p += 512) {
    int c = p / (EH2 / 2), u2 = p % (EH2 / 2);
    float2 v = w4f[p];
    s.e4p[u2][c] = packbf(v.x, v.y);
  }
  __syncthreads();

  float b3a = b3[2 * l], b3b = b3[2 * l + 1];
  float bias4 = b4[l];
  float gl = g[l], bl = bb[l];

  for (int j = w; j < NN; j += 8) {
    size_t off = ((size_t)bi * NN + j) * NE + l;
    float t0 = adjio[off];
    s.tb[w][l] = t0;
    float a0 = b3a, a1 = b3b;
    const float2* t2 = (const float2*)s.tb[w];
#pragma unroll 4
    for (int k2 = 0; k2 < NE / 2; ++k2) {
      float2 tv = t2[k2];
      uint2 wp = *(const uint2*)&s.e3p[k2][2 * l];
      a0 += tv.x * bflo(wp.x) + tv.y * bfhi(wp.x);
      a1 += tv.x * bflo(wp.y) + tv.y * bfhi(wp.y);
    }
    s.h2b[w][2 * l] = fmaxf(a0, 0.f);
    s.h2b[w][2 * l + 1] = fmaxf(a1, 0.f);
    float r = bias4;
    const float2* hh = (const float2*)s.h2b[w];
#pragma unroll 4
    for (int u2 = 0; u2 < EH2 / 2; ++u2) {
      float2 hv = hh[u2];
      u32 wp = s.e4p[u2][l];
      r += hv.x * bflo(wp) + hv.y * bfhi(wp);
    }
    float tv = t0 + r;
    float mean = wsum64(tv) * (1.f / NE);
    float dv = tv - mean;
    float var = wsum64(dv * dv) * (1.f / NE);
    float o = dv * rsqrtf(var + LN_EPS) * gl + bl;
    adjio[off] = o;  // FLOAT32 output
  }
}

extern "C" void kernel_launch(void* const* d_in, const int* in_sizes, int n_in,
                              void* d_out, int out_size, void* d_ws, size_t ws_size,
                              hipStream_t stream) {
  (void)in_sizes; (void)n_in; (void)out_size; (void)d_ws; (void)ws_size;
  // setup_inputs() dict insertion order (confirmed: in_sizes[0]==98304, R5)
  const float* x      = (const float*)d_in[0];
  const float* adj    = (const float*)d_in[1];
  const float* wnq    = (const float*)d_in[2];
  const float* wnk    = (const float*)d_in[3];
  const float* wnv    = (const float*)d_in[4];
  const float* weq    = (const float*)d_in[5];
  const float* wek    = (const float*)d_in[6];
  const float* wev    = (const float*)d_in[7];
  const float* nfc1_w = (const float*)d_in[8];
  const float* nfc1_b = (const float*)d_in[9];
  const float* ln1_g  = (const float*)d_in[10];
  const float* ln1_b  = (const float*)d_in[11];
  const float* nfc2_w = (const float*)d_in[12];
  const float* nfc2_b = (const float*)d_in[13];
  const float* nfc3_w = (const float*)d_in[14];
  const float* nfc3_b = (const float*)d_in[15];
  const float* ln2_g  = (const float*)d_in[16];
  const float* ln2_b  = (const float*)d_in[17];
  const float* efc1_w = (const float*)d_in[18];
  const float* efc1_b = (const float*)d_in[19];
  const float* efc2_w = (const float*)d_in[20];
  const float* efc2_b = (const float*)d_in[21];
  const float* eln1_g = (const float*)d_in[22];
  const float* eln1_b = (const float*)d_in[23];
  const float* efc3_w = (const float*)d_in[24];
  const float* efc3_b = (const float*)d_in[25];
  const float* efc4_w = (const float*)d_in[26];
  const float* efc4_b = (const float*)d_in[27];
  const float* eln2_g = (const float*)d_in[28];
  const float* eln2_b = (const float*)d_in[29];

  float* outf = (float*)d_out;          // FLOAT32 output buffer: [x ; adj]
  float* outadj = outf + XOUT_ELEMS;

  // f32 scratch in the tail of the adj-output region (dead until k_edge1,
  // by which time nq/nk/nv/att are all consumed). No d_ws usage.
  float* scratch = outf + OUT_ELEMS - SCRATCH_F32;
  float* nq  = scratch;
  float* nk  = scratch + XOUT_ELEMS;
  float* nv  = scratch + 2 * XOUT_ELEMS;
  float* att = scratch + 3 * XOUT_ELEMS;

  k_node_qkv<<<NB * NN, 128, 0, stream>>>(x, wnq, wnk, wnv, nq, nk, nv);
  k_attn<<<NB * NN, 384, 0, stream>>>(adj, weq, wek, wev, nq, nk, nv, att);
  k_node_ffn<<<NB * NN, 256, 0, stream>>>(x, att, nfc1_w, nfc1_b, ln1_g, ln1_b,
                                          nfc2_w, nfc2_b, nfc3_w, nfc3_b,
                                          ln2_g, ln2_b, outf);
  k_edge1<<<NB * NN, 256, 0, stream>>>(adj, outf, efc1_w, efc1_b, efc2_w, efc2_b,
                                       eln1_g, eln1_b, outadj);
  k_edge2<<<NB * NN, 512, 0, stream>>>(outadj, efc3_w, efc3_b, efc4_w, efc4_b,
                                       eln2_g, eln2_b);
}